// Round 1
// baseline (3711.836 us; speedup 1.0000x reference)
//
#include <hip/hip_runtime.h>
#include <math.h>

#define VOCAB 50257
#define VPAD  50432
#define DM    1024
#define NH    16
#define DKH   64
#define FF    4096
#define NL    4
#define SEQ   2048
#define BATCH 2
#define MROWS (BATCH*SEQ)

typedef __bf16 bf16_t;
typedef __bf16 bf16x8 __attribute__((ext_vector_type(8)));
typedef __bf16 bf16x4 __attribute__((ext_vector_type(4)));
typedef float  f32x4  __attribute__((ext_vector_type(4)));

typedef void as1_void __attribute__((address_space(1)));
typedef void as3_void __attribute__((address_space(3)));

__device__ __forceinline__ void gload_lds16(const void* g, void* l) {
  __builtin_amdgcn_global_load_lds((as1_void*)g, (as3_void*)l, 16, 0, 0);
}

// ---------------- embedding + positional encoding ----------------
__global__ __launch_bounds__(256) void embed_kernel(const int* __restrict__ x,
    const float* __restrict__ emb, float* __restrict__ h) {
  int row = blockIdx.x;            // 0..MROWS-1
  int s = row & (SEQ - 1);
  int d = threadIdx.x * 4;
  const float* e = emb + (size_t)x[row] * DM + d;
  float4 v = *(const float4*)e;
  float vin[4] = {v.x, v.y, v.z, v.w};
  float out[4];
#pragma unroll
  for (int j = 0; j < 4; ++j) {
    int dd = d + j;
    int i = dd >> 1;
    float freq = expf(-0.017988946039016376f * (float)i); // -2*ln(10000)/1024
    float ang = (float)s * freq;
    float pe = (dd & 1) ? cosf(ang) : sinf(ang);
    out[j] = vin[j] + pe;
  }
  *(float4*)(h + (size_t)row * DM + d) = make_float4(out[0], out[1], out[2], out[3]);
}

// ---------------- layernorm (f32 in -> bf16 out) ----------------
__global__ __launch_bounds__(256) void ln_kernel(const float* __restrict__ x,
    const float* __restrict__ g, const float* __restrict__ b, bf16_t* __restrict__ out) {
  int row = blockIdx.x;
  int tid = threadIdx.x, lane = tid & 63, wave = tid >> 6;
  const float* xr = x + (size_t)row * DM;
  float4 v = ((const float4*)xr)[tid];
  float s1 = v.x + v.y + v.z + v.w;
  float s2 = v.x * v.x + v.y * v.y + v.z * v.z + v.w * v.w;
#pragma unroll
  for (int d = 1; d < 64; d <<= 1) { s1 += __shfl_xor(s1, d); s2 += __shfl_xor(s2, d); }
  __shared__ float red[8];
  if (lane == 0) { red[wave] = s1; red[4 + wave] = s2; }
  __syncthreads();
  s1 = red[0] + red[1] + red[2] + red[3];
  s2 = red[4] + red[5] + red[6] + red[7];
  float mu = s1 * (1.0f / DM);
  float var = s2 * (1.0f / DM) - mu * mu;
  float rs = rsqrtf(var + 1e-5f);
  float4 gv = ((const float4*)g)[tid];
  float4 bv = ((const float4*)b)[tid];
  bf16x4 o;
  o[0] = (bf16_t)((v.x - mu) * rs * gv.x + bv.x);
  o[1] = (bf16_t)((v.y - mu) * rs * gv.y + bv.y);
  o[2] = (bf16_t)((v.z - mu) * rs * gv.z + bv.z);
  o[3] = (bf16_t)((v.w - mu) * rs * gv.w + bv.w);
  *(bf16x4*)(out + (size_t)row * DM + tid * 4) = o;
}

// ------------- transpose + cast: f32 [K][N] -> bf16 [Npad][K], pad rows zero -------------
__global__ __launch_bounds__(256) void transpose_cast_kernel(const float* __restrict__ in,
    bf16_t* __restrict__ out, int K, int N, int Npad) {
  __shared__ float tile[32][33];
  int n0 = blockIdx.x * 32, k0 = blockIdx.y * 32;
  int tx = threadIdx.x & 31, ty = threadIdx.x >> 5;  // ty 0..7
#pragma unroll
  for (int kk = ty; kk < 32; kk += 8) {
    int n = n0 + tx;
    tile[kk][tx] = (n < N) ? in[(size_t)(k0 + kk) * N + n] : 0.f;
  }
  __syncthreads();
#pragma unroll
  for (int nn = ty; nn < 32; nn += 8) {
    out[(size_t)(n0 + nn) * K + k0 + tx] = (bf16_t)tile[tx][nn];
  }
}

// ---------------- GEMM: A[M,K]bf16 x Bt[N,K]bf16 -> C[M,ldc] ----------------
// 128x128 tile, BK=32, 4 waves (2x2 of 64x64), mfma_f32_16x16x32_bf16.
// LDS layout: 16B units, unit index = k8*128 + row (linear for global_load_lds,
// conflict-free for ds_read_b128 fragment reads).
__global__ __launch_bounds__(256) void gemm_kernel(
    const bf16_t* __restrict__ A, const bf16_t* __restrict__ Bt, int K,
    const float* __restrict__ bias, const float* __restrict__ Rsd,
    float* Cf, bf16_t* Cb, int ldc, int Nvalid, int relu) {
  __shared__ __align__(16) bf16_t lA[4096];  // 8 KB
  __shared__ __align__(16) bf16_t lB[4096];  // 8 KB
  int tid = threadIdx.x, lane = tid & 63, wave = tid >> 6;
  int g = lane >> 4, r = lane & 15;
  int wr = wave >> 1, wc = wave & 1;
  int m0 = blockIdx.x * 128, n0 = blockIdx.y * 128;

  f32x4 zero = {0.f, 0.f, 0.f, 0.f};
  f32x4 acc[4][4];
#pragma unroll
  for (int i = 0; i < 4; ++i)
#pragma unroll
    for (int j = 0; j < 4; ++j) acc[i][j] = zero;

  const bf16_t* Abase = A + (size_t)m0 * K;
  const bf16_t* Bbase = Bt + (size_t)n0 * K;

  for (int k0 = 0; k0 < K; k0 += 32) {
    __syncthreads();
#pragma unroll
    for (int c = 0; c < 2; ++c) {
      int u = c * 256 + tid;
      int k8 = u >> 7, rw = u & 127;
      gload_lds16(Abase + (size_t)rw * K + k0 + k8 * 8, &lA[(c * 256 + wave * 64) * 8]);
      gload_lds16(Bbase + (size_t)rw * K + k0 + k8 * 8, &lB[(c * 256 + wave * 64) * 8]);
    }
    __syncthreads();
    bf16x8 af[4], bfr[4];
#pragma unroll
    for (int mr = 0; mr < 4; ++mr)
      af[mr] = *(const bf16x8*)&lA[(g * 128 + wr * 64 + mr * 16 + r) * 8];
#pragma unroll
    for (int nr = 0; nr < 4; ++nr)
      bfr[nr] = *(const bf16x8*)&lB[(g * 128 + wc * 64 + nr * 16 + r) * 8];
#pragma unroll
    for (int mr = 0; mr < 4; ++mr)
#pragma unroll
      for (int nr = 0; nr < 4; ++nr)
        acc[mr][nr] = __builtin_amdgcn_mfma_f32_16x16x32_bf16(af[mr], bfr[nr], acc[mr][nr], 0, 0, 0);
  }

#pragma unroll
  for (int mr = 0; mr < 4; ++mr) {
    int row = m0 + wr * 64 + mr * 16 + g * 4;
#pragma unroll
    for (int nr = 0; nr < 4; ++nr) {
      int col = n0 + wc * 64 + nr * 16 + r;
      if (col < Nvalid) {
        float bval = bias ? bias[col] : 0.f;
#pragma unroll
        for (int i = 0; i < 4; ++i) {
          float vv = acc[mr][nr][i] + bval;
          if (relu) vv = fmaxf(vv, 0.f);
          size_t idx = (size_t)(row + i) * ldc + col;
          if (Rsd) vv += Rsd[idx];
          if (Cf) Cf[idx] = vv;
          if (Cb) Cb[idx] = (bf16_t)vv;
        }
      }
    }
  }
}

// ---------------- flash attention (causal), bf16 in/out ----------------
// grid (SEQ/64, NH, BATCH), 256 thr = 4 waves; wave handles 16 q-rows.
__global__ __launch_bounds__(256) void attn_kernel(const bf16_t* __restrict__ Qg,
    const bf16_t* __restrict__ Kg, const bf16_t* __restrict__ Vg, bf16_t* __restrict__ Og) {
  int bq = blockIdx.x, hh = blockIdx.y, bb = blockIdx.z;
  int tid = threadIdx.x, lane = tid & 63, wave = tid >> 6;
  int g = lane >> 4, r = lane & 15;
  __shared__ __align__(16) bf16_t Kl[4096];      // units [dk8(8)][krow(64)]
  __shared__ __align__(16) bf16_t Vl[4096];      // units [kr8(8)][dk(64)] (transposed V)
  __shared__ __align__(16) bf16_t Pl[4][1024];   // per-wave units [k8(8)][qrow(16)]

  size_t base = (size_t)bb * SEQ * DM + hh * DKH;
  int q0 = bq * 64 + wave * 16;
  const bf16_t* qrowp = Qg + base + (size_t)(q0 + r) * DM;
  bf16x8 qf0 = *(const bf16x8*)(qrowp + g * 8);
  bf16x8 qf1 = *(const bf16x8*)(qrowp + 32 + g * 8);

  f32x4 zero = {0.f, 0.f, 0.f, 0.f};
  f32x4 accO[4];
#pragma unroll
  for (int dt = 0; dt < 4; ++dt) accO[dt] = zero;
  float m_i[4], l_i[4];
#pragma unroll
  for (int i = 0; i < 4; ++i) { m_i[i] = -1e30f; l_i[i] = 0.f; }
  const float scale = 0.125f;  // 1/sqrt(64)

  for (int kb = 0; kb <= bq; ++kb) {
    __syncthreads();
    // stage K: unit u = dk8*64 + krow
#pragma unroll
    for (int c = 0; c < 2; ++c) {
      int u = c * 256 + tid;
      int dk8 = u >> 6, krow = u & 63;
      gload_lds16(Kg + base + (size_t)(kb * 64 + krow) * DM + dk8 * 8,
                  &Kl[(c * 256 + wave * 64) * 8]);
    }
    // stage V transposed: unit(kr8,dk) holds V[kr8*8+t][dk]
#pragma unroll
    for (int c = 0; c < 2; ++c) {
      int u = c * 256 + tid;
      int krow = u >> 3, dk8 = u & 7;
      bf16x8 vv = *(const bf16x8*)(Vg + base + (size_t)(kb * 64 + krow) * DM + dk8 * 8);
#pragma unroll
      for (int j = 0; j < 8; ++j)
        Vl[((krow >> 3) * 64 + dk8 * 8 + j) * 8 + (krow & 7)] = vv[j];
    }
    __syncthreads();

    // scores: 16x64 per wave
    f32x4 sc[4];
#pragma unroll
    for (int ct = 0; ct < 4; ++ct) {
      bf16x8 kf0 = *(const bf16x8*)&Kl[((0 + g) * 64 + ct * 16 + r) * 8];
      bf16x8 kf1 = *(const bf16x8*)&Kl[((4 + g) * 64 + ct * 16 + r) * 8];
      f32x4 s = zero;
      s = __builtin_amdgcn_mfma_f32_16x16x32_bf16(qf0, kf0, s, 0, 0, 0);
      s = __builtin_amdgcn_mfma_f32_16x16x32_bf16(qf1, kf1, s, 0, 0, 0);
      sc[ct] = s;
    }

    // online softmax per row (row = g*4+i), reduce across 16 lanes (r)
#pragma unroll
    for (int i = 0; i < 4; ++i) {
      int qglob = q0 + g * 4 + i;
      float mx = m_i[i];
#pragma unroll
      for (int ct = 0; ct < 4; ++ct) {
        int kglob = kb * 64 + ct * 16 + r;
        float s = sc[ct][i] * scale;
        s = (kglob <= qglob) ? s : -1e30f;
        sc[ct][i] = s;
        mx = fmaxf(mx, s);
      }
#pragma unroll
      for (int d = 1; d < 16; d <<= 1) mx = fmaxf(mx, __shfl_xor(mx, d));
      float scl = expf(m_i[i] - mx);
      l_i[i] *= scl;
      m_i[i] = mx;
      float rsum = 0.f;
#pragma unroll
      for (int ct = 0; ct < 4; ++ct) {
        float p = expf(sc[ct][i] - mx);
        sc[ct][i] = p;
        rsum += p;
      }
#pragma unroll
      for (int d = 1; d < 16; d <<= 1) rsum += __shfl_xor(rsum, d);
      l_i[i] += rsum;
#pragma unroll
      for (int dt = 0; dt < 4; ++dt) accO[dt][i] *= scl;
    }

    // P -> LDS (bf16), units [k8][qrow]
#pragma unroll
    for (int ct = 0; ct < 4; ++ct) {
      int kcol = ct * 16 + r;
#pragma unroll
      for (int i = 0; i < 4; ++i)
        Pl[wave][((kcol >> 3) * 16 + g * 4 + i) * 8 + (kcol & 7)] = (bf16_t)sc[ct][i];
    }

    // PV: O += P[16,64] * V[64,64]
    bf16x8 pa0 = *(const bf16x8*)&Pl[wave][((0 + g) * 16 + r) * 8];
    bf16x8 pa1 = *(const bf16x8*)&Pl[wave][((4 + g) * 16 + r) * 8];
#pragma unroll
    for (int dt = 0; dt < 4; ++dt) {
      bf16x8 vb0 = *(const bf16x8*)&Vl[((0 + g) * 64 + dt * 16 + r) * 8];
      bf16x8 vb1 = *(const bf16x8*)&Vl[((4 + g) * 64 + dt * 16 + r) * 8];
      accO[dt] = __builtin_amdgcn_mfma_f32_16x16x32_bf16(pa0, vb0, accO[dt], 0, 0, 0);
      accO[dt] = __builtin_amdgcn_mfma_f32_16x16x32_bf16(pa1, vb1, accO[dt], 0, 0, 0);
    }
  }

#pragma unroll
  for (int dt = 0; dt < 4; ++dt)
#pragma unroll
    for (int i = 0; i < 4; ++i) {
      int rowq = q0 + g * 4 + i;
      Og[base + (size_t)rowq * DM + dt * 16 + r] = (bf16_t)(accO[dt][i] / l_i[i]);
    }
}

// ---------------- launcher ----------------
extern "C" void kernel_launch(void* const* d_in, const int* in_sizes, int n_in,
                              void* d_out, int out_size, void* d_ws, size_t ws_size,
                              hipStream_t stream) {
  const int*   x      = (const int*)d_in[0];
  const float* emb    = (const float*)d_in[1];
  const float* ln1_g  = (const float*)d_in[2];
  const float* ln1_b  = (const float*)d_in[3];
  const float* wq     = (const float*)d_in[4];
  const float* wk     = (const float*)d_in[5];
  const float* wv     = (const float*)d_in[6];
  const float* wo     = (const float*)d_in[7];
  const float* ln2_g  = (const float*)d_in[8];
  const float* ln2_b  = (const float*)d_in[9];
  const float* w1     = (const float*)d_in[10];
  const float* b1     = (const float*)d_in[11];
  const float* w2     = (const float*)d_in[12];
  const float* b2     = (const float*)d_in[13];
  const float* lnf_g  = (const float*)d_in[14];
  const float* lnf_b  = (const float*)d_in[15];
  const float* head_w = (const float*)d_in[16];
  const float* head_b = (const float*)d_in[17];
  float* out = (float*)d_out;

  char* ws = (char*)d_ws;
  size_t off = 0;
  auto alloc = [&](size_t bytes) -> void* {
    void* p = ws + off;
    off += (bytes + 255) & ~(size_t)255;
    return p;
  };
  float*  h     = (float*)alloc((size_t)MROWS * DM * 4);
  bf16_t* hn    = (bf16_t*)alloc((size_t)MROWS * DM * 2);
  bf16_t* qb    = (bf16_t*)alloc((size_t)MROWS * DM * 2);
  bf16_t* kbuf  = (bf16_t*)alloc((size_t)MROWS * DM * 2);
  bf16_t* vbuf  = (bf16_t*)alloc((size_t)MROWS * DM * 2);
  bf16_t* atb   = (bf16_t*)alloc((size_t)MROWS * DM * 2);
  bf16_t* ffn1  = (bf16_t*)alloc((size_t)MROWS * FF * 2);
  bf16_t* wT    = (bf16_t*)alloc((size_t)DM * FF * 2);
  bf16_t* headT = (bf16_t*)alloc((size_t)VPAD * DM * 2);

  embed_kernel<<<MROWS, 256, 0, stream>>>(x, emb, h);

  for (int l = 0; l < NL; ++l) {
    ln_kernel<<<MROWS, 256, 0, stream>>>(h, ln1_g + l * DM, ln1_b + l * DM, hn);

    transpose_cast_kernel<<<dim3(DM / 32, DM / 32), 256, 0, stream>>>(
        wq + (size_t)l * DM * DM, wT, DM, DM, DM);
    gemm_kernel<<<dim3(MROWS / 128, DM / 128), 256, 0, stream>>>(
        hn, wT, DM, nullptr, nullptr, nullptr, qb, DM, DM, 0);

    transpose_cast_kernel<<<dim3(DM / 32, DM / 32), 256, 0, stream>>>(
        wk + (size_t)l * DM * DM, wT, DM, DM, DM);
    gemm_kernel<<<dim3(MROWS / 128, DM / 128), 256, 0, stream>>>(
        hn, wT, DM, nullptr, nullptr, nullptr, kbuf, DM, DM, 0);

    transpose_cast_kernel<<<dim3(DM / 32, DM / 32), 256, 0, stream>>>(
        wv + (size_t)l * DM * DM, wT, DM, DM, DM);
    gemm_kernel<<<dim3(MROWS / 128, DM / 128), 256, 0, stream>>>(
        hn, wT, DM, nullptr, nullptr, nullptr, vbuf, DM, DM, 0);

    attn_kernel<<<dim3(SEQ / 64, NH, BATCH), 256, 0, stream>>>(qb, kbuf, vbuf, atb);

    transpose_cast_kernel<<<dim3(DM / 32, DM / 32), 256, 0, stream>>>(
        wo + (size_t)l * DM * DM, wT, DM, DM, DM);
    gemm_kernel<<<dim3(MROWS / 128, DM / 128), 256, 0, stream>>>(
        atb, wT, DM, nullptr, h, h, nullptr, DM, DM, 0);

    ln_kernel<<<MROWS, 256, 0, stream>>>(h, ln2_g + l * DM, ln2_b + l * DM, hn);

    transpose_cast_kernel<<<dim3(FF / 32, DM / 32), 256, 0, stream>>>(
        w1 + (size_t)l * DM * FF, wT, DM, FF, FF);
    gemm_kernel<<<dim3(MROWS / 128, FF / 128), 256, 0, stream>>>(
        hn, wT, DM, b1 + (size_t)l * FF, nullptr, nullptr, ffn1, FF, FF, 1);

    transpose_cast_kernel<<<dim3(DM / 32, FF / 32), 256, 0, stream>>>(
        w2 + (size_t)l * FF * DM, wT, FF, DM, DM);
    gemm_kernel<<<dim3(MROWS / 128, DM / 128), 256, 0, stream>>>(
        ffn1, wT, FF, b2 + (size_t)l * DM, h, h, nullptr, DM, DM, 0);
  }

  ln_kernel<<<MROWS, 256, 0, stream>>>(h, lnf_g, lnf_b, hn);
  transpose_cast_kernel<<<dim3(VPAD / 32, DM / 32), 256, 0, stream>>>(
      head_w, headT, DM, VOCAB, VPAD);
  gemm_kernel<<<dim3(MROWS / 128, VPAD / 128), 256, 0, stream>>>(
      hn, headT, DM, head_b, nullptr, out, nullptr, VOCAB, VOCAB, 0);
}

// Round 2
// 3568.347 us; speedup vs baseline: 1.0402x; 1.0402x over previous
//
#include <hip/hip_runtime.h>
#include <math.h>

#define VOCAB 50257
#define VPAD  50432
#define DM    1024
#define NH    16
#define DKH   64
#define FF    4096
#define NL    4
#define SEQ   2048
#define BATCH 2
#define MROWS (BATCH*SEQ)

typedef __bf16 bf16_t;
typedef __bf16 bf16x8 __attribute__((ext_vector_type(8)));
typedef __bf16 bf16x4 __attribute__((ext_vector_type(4)));
typedef float  f32x4  __attribute__((ext_vector_type(4)));

typedef void as1_void __attribute__((address_space(1)));
typedef void as3_void __attribute__((address_space(3)));

__device__ __forceinline__ void gload_lds16(const void* g, void* l) {
  __builtin_amdgcn_global_load_lds((as1_void*)g, (as3_void*)l, 16, 0, 0);
}

// ---------------- embedding + positional encoding ----------------
__global__ __launch_bounds__(256) void embed_kernel(const int* __restrict__ x,
    const float* __restrict__ emb, float* __restrict__ h) {
  int row = blockIdx.x;            // 0..MROWS-1
  int s = row & (SEQ - 1);
  int d = threadIdx.x * 4;
  const float* e = emb + (size_t)x[row] * DM + d;
  float4 v = *(const float4*)e;
  float vin[4] = {v.x, v.y, v.z, v.w};
  float out[4];
#pragma unroll
  for (int j = 0; j < 4; ++j) {
    int dd = d + j;
    int i = dd >> 1;
    float freq = expf(-0.017988946039016376f * (float)i); // -2*ln(10000)/1024
    float ang = (float)s * freq;
    float pe = (dd & 1) ? cosf(ang) : sinf(ang);
    out[j] = vin[j] + pe;
  }
  *(float4*)(h + (size_t)row * DM + d) = make_float4(out[0], out[1], out[2], out[3]);
}

// ---------------- layernorm (f32 in -> bf16 out) ----------------
__global__ __launch_bounds__(256) void ln_kernel(const float* __restrict__ x,
    const float* __restrict__ g, const float* __restrict__ b, bf16_t* __restrict__ out) {
  int row = blockIdx.x;
  int tid = threadIdx.x, lane = tid & 63, wave = tid >> 6;
  const float* xr = x + (size_t)row * DM;
  float4 v = ((const float4*)xr)[tid];
  float s1 = v.x + v.y + v.z + v.w;
  float s2 = v.x * v.x + v.y * v.y + v.z * v.z + v.w * v.w;
#pragma unroll
  for (int d = 1; d < 64; d <<= 1) { s1 += __shfl_xor(s1, d); s2 += __shfl_xor(s2, d); }
  __shared__ float red[8];
  if (lane == 0) { red[wave] = s1; red[4 + wave] = s2; }
  __syncthreads();
  s1 = red[0] + red[1] + red[2] + red[3];
  s2 = red[4] + red[5] + red[6] + red[7];
  float mu = s1 * (1.0f / DM);
  float var = s2 * (1.0f / DM) - mu * mu;
  float rs = rsqrtf(var + 1e-5f);
  float4 gv = ((const float4*)g)[tid];
  float4 bv = ((const float4*)b)[tid];
  bf16x4 o;
  o[0] = (bf16_t)((v.x - mu) * rs * gv.x + bv.x);
  o[1] = (bf16_t)((v.y - mu) * rs * gv.y + bv.y);
  o[2] = (bf16_t)((v.z - mu) * rs * gv.z + bv.z);
  o[3] = (bf16_t)((v.w - mu) * rs * gv.w + bv.w);
  *(bf16x4*)(out + (size_t)row * DM + tid * 4) = o;
}

// ------------- transpose + cast: f32 [K][N] -> bf16 [Npad][K], pad rows zero -------------
__global__ __launch_bounds__(256) void transpose_cast_kernel(const float* __restrict__ in,
    bf16_t* __restrict__ out, int K, int N, int Npad) {
  __shared__ float tile[32][33];
  int n0 = blockIdx.x * 32, k0 = blockIdx.y * 32;
  int tx = threadIdx.x & 31, ty = threadIdx.x >> 5;  // ty 0..7
#pragma unroll
  for (int kk = ty; kk < 32; kk += 8) {
    int n = n0 + tx;
    tile[kk][tx] = (n < N) ? in[(size_t)(k0 + kk) * N + n] : 0.f;
  }
  __syncthreads();
#pragma unroll
  for (int nn = ty; nn < 32; nn += 8) {
    out[(size_t)(n0 + nn) * K + k0 + tx] = (bf16_t)tile[tx][nn];
  }
}

// ---------------- GEMM: A[M,K]bf16 x Bt[N,K]bf16 -> C[M,ldc] ----------------
// 128x128 tile, BK=64, 4 waves (2x2 of 64x64), double-buffered LDS (64 KB),
// counted vmcnt(8) so next-tile global_load_lds stay in flight across barriers.
// LDS unit layout (16B units): unit = k8*128 + row — linear for global_load_lds,
// conflict-free for ds_read_b128 fragment reads (0 conflicts measured R1).
__global__ __launch_bounds__(256) void gemm_kernel(
    const bf16_t* __restrict__ A, const bf16_t* __restrict__ Bt, int K,
    const float* __restrict__ bias, const float* __restrict__ Rsd,
    float* Cf, bf16_t* Cb, int ldc, int Nvalid, int relu, int gridM, int gridN) {
  __shared__ __align__(16) bf16_t lA0[8192], lA1[8192];  // 16 KB each
  __shared__ __align__(16) bf16_t lB0[8192], lB1[8192];

  // bijective XCD swizzle (m204)
  int nwg = gridM * gridN;
  int orig = blockIdx.x;
  int q = nwg >> 3, rr = nwg & 7;
  int xcd = orig & 7, idx = orig >> 3;
  int swz = (xcd < rr ? xcd * (q + 1) : rr * (q + 1) + (xcd - rr) * q) + idx;
  int bm = swz % gridM, bn = swz / gridM;   // bm fastest: consecutive blocks share B-panel

  int tid = threadIdx.x, lane = tid & 63, wave = tid >> 6;
  int g = lane >> 4, r = lane & 15;
  int wr = wave >> 1, wc = wave & 1;
  int m0 = bm * 128, n0 = bn * 128;

  f32x4 zero = {0.f, 0.f, 0.f, 0.f};
  f32x4 acc[4][4];
#pragma unroll
  for (int i = 0; i < 4; ++i)
#pragma unroll
    for (int j = 0; j < 4; ++j) acc[i][j] = zero;

  const bf16_t* Abase = A + (size_t)m0 * K;
  const bf16_t* Bbase = Bt + (size_t)n0 * K;

  // stage one K-tile (BK=64): per thread 4 A units + 4 B units (16B each)
  auto stage = [&](bf16_t* la, bf16_t* lb, int k0) {
#pragma unroll
    for (int c = 0; c < 4; ++c) {
      int u = c * 256 + tid;
      int k8 = u >> 7, rw = u & 127;
      gload_lds16(Abase + (size_t)rw * K + k0 + k8 * 8, &la[(c * 256 + wave * 64) * 8]);
    }
#pragma unroll
    for (int c = 0; c < 4; ++c) {
      int u = c * 256 + tid;
      int k8 = u >> 7, rw = u & 127;
      gload_lds16(Bbase + (size_t)rw * K + k0 + k8 * 8, &lb[(c * 256 + wave * 64) * 8]);
    }
  };

  int NT = K >> 6;
  stage(lA0, lB0, 0);

  for (int t = 0; t < NT; ++t) {
    const bf16_t* la = (t & 1) ? lA1 : lA0;
    const bf16_t* lb = (t & 1) ? lB1 : lB0;
    if (t + 1 < NT) {
      stage((t & 1) ? lA0 : lA1, (t & 1) ? lB0 : lB1, (t + 1) << 6);
      asm volatile("s_waitcnt vmcnt(8)" ::: "memory");   // cur tile's 8 loads done; next 8 in flight
    } else {
      asm volatile("s_waitcnt vmcnt(0)" ::: "memory");
    }
    __builtin_amdgcn_s_barrier();
    asm volatile("" ::: "memory");

    bf16x8 af[4][2], bfr[4][2];
#pragma unroll
    for (int mr = 0; mr < 4; ++mr)
#pragma unroll
      for (int kk = 0; kk < 2; ++kk)
        af[mr][kk] = *(const bf16x8*)&la[((kk * 4 + g) * 128 + wr * 64 + mr * 16 + r) * 8];
#pragma unroll
    for (int nr = 0; nr < 4; ++nr)
#pragma unroll
      for (int kk = 0; kk < 2; ++kk)
        bfr[nr][kk] = *(const bf16x8*)&lb[((kk * 4 + g) * 128 + wc * 64 + nr * 16 + r) * 8];

    __builtin_amdgcn_s_setprio(1);
#pragma unroll
    for (int mr = 0; mr < 4; ++mr)
#pragma unroll
      for (int nr = 0; nr < 4; ++nr) {
        acc[mr][nr] = __builtin_amdgcn_mfma_f32_16x16x32_bf16(af[mr][0], bfr[nr][0], acc[mr][nr], 0, 0, 0);
        acc[mr][nr] = __builtin_amdgcn_mfma_f32_16x16x32_bf16(af[mr][1], bfr[nr][1], acc[mr][nr], 0, 0, 0);
      }
    __builtin_amdgcn_s_setprio(0);

    asm volatile("" ::: "memory");
    __builtin_amdgcn_s_barrier();     // all waves done reading this buffer
    asm volatile("" ::: "memory");
  }

#pragma unroll
  for (int mr = 0; mr < 4; ++mr) {
    int row = m0 + wr * 64 + mr * 16 + g * 4;
#pragma unroll
    for (int nr = 0; nr < 4; ++nr) {
      int col = n0 + wc * 64 + nr * 16 + r;
      if (col < Nvalid) {
        float bval = bias ? bias[col] : 0.f;
#pragma unroll
        for (int i = 0; i < 4; ++i) {
          float vv = acc[mr][nr][i] + bval;
          if (relu) vv = fmaxf(vv, 0.f);
          size_t idx = (size_t)(row + i) * ldc + col;
          if (Rsd) vv += Rsd[idx];
          if (Cf) Cf[idx] = vv;
          if (Cb) Cb[idx] = (bf16_t)vv;
        }
      }
    }
  }
}

// ---------------- flash attention (causal), bf16 in/out ----------------
// grid (SEQ/64, NH, BATCH), 256 thr = 4 waves; wave handles 16 q-rows.
// Q/K/V read from the fused qkv buffer with row stride ldq.
__global__ __launch_bounds__(256) void attn_kernel(const bf16_t* __restrict__ Qg,
    const bf16_t* __restrict__ Kg, const bf16_t* __restrict__ Vg, bf16_t* __restrict__ Og,
    int ldq) {
  int bq = blockIdx.x, hh = blockIdx.y, bb = blockIdx.z;
  int tid = threadIdx.x, lane = tid & 63, wave = tid >> 6;
  int g = lane >> 4, r = lane & 15;
  __shared__ __align__(16) bf16_t Kl[4096];      // units [dk8(8)][krow(64)]
  __shared__ __align__(16) bf16_t Vl[4096];      // units [kr8(8)][dk(64)] (transposed V)
  __shared__ __align__(16) bf16_t Pl[4][1024];   // per-wave units [k8(8)][qrow(16)]

  size_t base = (size_t)bb * SEQ * ldq + hh * DKH;
  size_t baseO = (size_t)bb * SEQ * DM + hh * DKH;
  int q0 = bq * 64 + wave * 16;
  const bf16_t* qrowp = Qg + base + (size_t)(q0 + r) * ldq;
  bf16x8 qf0 = *(const bf16x8*)(qrowp + g * 8);
  bf16x8 qf1 = *(const bf16x8*)(qrowp + 32 + g * 8);

  f32x4 zero = {0.f, 0.f, 0.f, 0.f};
  f32x4 accO[4];
#pragma unroll
  for (int dt = 0; dt < 4; ++dt) accO[dt] = zero;
  float m_i[4], l_i[4];
#pragma unroll
  for (int i = 0; i < 4; ++i) { m_i[i] = -1e30f; l_i[i] = 0.f; }
  const float scale = 0.125f;  // 1/sqrt(64)

  for (int kb = 0; kb <= bq; ++kb) {
    __syncthreads();
    // stage K: unit u = dk8*64 + krow
#pragma unroll
    for (int c = 0; c < 2; ++c) {
      int u = c * 256 + tid;
      int dk8 = u >> 6, krow = u & 63;
      gload_lds16(Kg + base + (size_t)(kb * 64 + krow) * ldq + dk8 * 8,
                  &Kl[(c * 256 + wave * 64) * 8]);
    }
    // stage V transposed: unit(kr8,dk) holds V[kr8*8+t][dk]
#pragma unroll
    for (int c = 0; c < 2; ++c) {
      int u = c * 256 + tid;
      int krow = u >> 3, dk8 = u & 7;
      bf16x8 vv = *(const bf16x8*)(Vg + base + (size_t)(kb * 64 + krow) * ldq + dk8 * 8);
#pragma unroll
      for (int j = 0; j < 8; ++j)
        Vl[((krow >> 3) * 64 + dk8 * 8 + j) * 8 + (krow & 7)] = vv[j];
    }
    __syncthreads();

    // scores: 16x64 per wave
    f32x4 sc[4];
#pragma unroll
    for (int ct = 0; ct < 4; ++ct) {
      bf16x8 kf0 = *(const bf16x8*)&Kl[((0 + g) * 64 + ct * 16 + r) * 8];
      bf16x8 kf1 = *(const bf16x8*)&Kl[((4 + g) * 64 + ct * 16 + r) * 8];
      f32x4 s = zero;
      s = __builtin_amdgcn_mfma_f32_16x16x32_bf16(qf0, kf0, s, 0, 0, 0);
      s = __builtin_amdgcn_mfma_f32_16x16x32_bf16(qf1, kf1, s, 0, 0, 0);
      sc[ct] = s;
    }

    // online softmax per row (row = g*4+i), reduce across 16 lanes (r)
#pragma unroll
    for (int i = 0; i < 4; ++i) {
      int qglob = q0 + g * 4 + i;
      float mx = m_i[i];
#pragma unroll
      for (int ct = 0; ct < 4; ++ct) {
        int kglob = kb * 64 + ct * 16 + r;
        float s = sc[ct][i] * scale;
        s = (kglob <= qglob) ? s : -1e30f;
        sc[ct][i] = s;
        mx = fmaxf(mx, s);
      }
#pragma unroll
      for (int d = 1; d < 16; d <<= 1) mx = fmaxf(mx, __shfl_xor(mx, d));
      float scl = expf(m_i[i] - mx);
      l_i[i] *= scl;
      m_i[i] = mx;
      float rsum = 0.f;
#pragma unroll
      for (int ct = 0; ct < 4; ++ct) {
        float p = expf(sc[ct][i] - mx);
        sc[ct][i] = p;
        rsum += p;
      }
#pragma unroll
      for (int d = 1; d < 16; d <<= 1) rsum += __shfl_xor(rsum, d);
      l_i[i] += rsum;
#pragma unroll
      for (int dt = 0; dt < 4; ++dt) accO[dt][i] *= scl;
    }

    // P -> LDS (bf16), units [k8][qrow]
#pragma unroll
    for (int ct = 0; ct < 4; ++ct) {
      int kcol = ct * 16 + r;
#pragma unroll
      for (int i = 0; i < 4; ++i)
        Pl[wave][((kcol >> 3) * 16 + g * 4 + i) * 8 + (kcol & 7)] = (bf16_t)sc[ct][i];
    }

    // PV: O += P[16,64] * V[64,64]
    bf16x8 pa0 = *(const bf16x8*)&Pl[wave][((0 + g) * 16 + r) * 8];
    bf16x8 pa1 = *(const bf16x8*)&Pl[wave][((4 + g) * 16 + r) * 8];
#pragma unroll
    for (int dt = 0; dt < 4; ++dt) {
      bf16x8 vb0 = *(const bf16x8*)&Vl[((0 + g) * 64 + dt * 16 + r) * 8];
      bf16x8 vb1 = *(const bf16x8*)&Vl[((4 + g) * 64 + dt * 16 + r) * 8];
      accO[dt] = __builtin_amdgcn_mfma_f32_16x16x32_bf16(pa0, vb0, accO[dt], 0, 0, 0);
      accO[dt] = __builtin_amdgcn_mfma_f32_16x16x32_bf16(pa1, vb1, accO[dt], 0, 0, 0);
    }
  }

#pragma unroll
  for (int dt = 0; dt < 4; ++dt)
#pragma unroll
    for (int i = 0; i < 4; ++i) {
      int rowq = q0 + g * 4 + i;
      Og[baseO + (size_t)rowq * DM + dt * 16 + r] = (bf16_t)(accO[dt][i] / l_i[i]);
    }
}

// ---------------- launcher ----------------
static inline void launch_gemm(const bf16_t* A, const bf16_t* Bt, int K,
    const float* bias, const float* Rsd, float* Cf, bf16_t* Cb,
    int ldc, int Nvalid, int relu, int M, int Npad, hipStream_t stream) {
  int gridM = M / 128, gridN = Npad / 128;
  gemm_kernel<<<dim3(gridM * gridN), 256, 0, stream>>>(
      A, Bt, K, bias, Rsd, Cf, Cb, ldc, Nvalid, relu, gridM, gridN);
}

extern "C" void kernel_launch(void* const* d_in, const int* in_sizes, int n_in,
                              void* d_out, int out_size, void* d_ws, size_t ws_size,
                              hipStream_t stream) {
  const int*   x      = (const int*)d_in[0];
  const float* emb    = (const float*)d_in[1];
  const float* ln1_g  = (const float*)d_in[2];
  const float* ln1_b  = (const float*)d_in[3];
  const float* wq     = (const float*)d_in[4];
  const float* wk     = (const float*)d_in[5];
  const float* wv     = (const float*)d_in[6];
  const float* wo     = (const float*)d_in[7];
  const float* ln2_g  = (const float*)d_in[8];
  const float* ln2_b  = (const float*)d_in[9];
  const float* w1     = (const float*)d_in[10];
  const float* b1     = (const float*)d_in[11];
  const float* w2     = (const float*)d_in[12];
  const float* b2     = (const float*)d_in[13];
  const float* lnf_g  = (const float*)d_in[14];
  const float* lnf_b  = (const float*)d_in[15];
  const float* head_w = (const float*)d_in[16];
  const float* head_b = (const float*)d_in[17];
  float* out = (float*)d_out;

  char* ws = (char*)d_ws;
  size_t off = 0;
  auto alloc = [&](size_t bytes) -> void* {
    void* p = ws + off;
    off += (bytes + 255) & ~(size_t)255;
    return p;
  };
  float*  h     = (float*)alloc((size_t)MROWS * DM * 4);
  bf16_t* hn    = (bf16_t*)alloc((size_t)MROWS * DM * 2);
  bf16_t* qkv   = (bf16_t*)alloc((size_t)MROWS * 3 * DM * 2);
  bf16_t* atb   = (bf16_t*)alloc((size_t)MROWS * DM * 2);
  bf16_t* ffn1  = (bf16_t*)alloc((size_t)MROWS * FF * 2);
  bf16_t* headT = (bf16_t*)alloc((size_t)VPAD * DM * 2);
  // per-layer transposed-weight buffers alias into headT (headT written only at the end)
  bf16_t* wqkvT = headT;                               // 3072x1024 bf16 = 6 MB
  bf16_t* wT    = headT + (size_t)4 * DM * DM;         // up to 8 MB (FF transposes)

  embed_kernel<<<MROWS, 256, 0, stream>>>(x, emb, h);

  for (int l = 0; l < NL; ++l) {
    ln_kernel<<<MROWS, 256, 0, stream>>>(h, ln1_g + l * DM, ln1_b + l * DM, hn);

    // fused QKV: wqkvT = [wq^T; wk^T; wv^T]  (3072 x 1024)
    transpose_cast_kernel<<<dim3(DM / 32, DM / 32), 256, 0, stream>>>(
        wq + (size_t)l * DM * DM, wqkvT, DM, DM, DM);
    transpose_cast_kernel<<<dim3(DM / 32, DM / 32), 256, 0, stream>>>(
        wk + (size_t)l * DM * DM, wqkvT + (size_t)DM * DM, DM, DM, DM);
    transpose_cast_kernel<<<dim3(DM / 32, DM / 32), 256, 0, stream>>>(
        wv + (size_t)l * DM * DM, wqkvT + (size_t)2 * DM * DM, DM, DM, DM);
    launch_gemm(hn, wqkvT, DM, nullptr, nullptr, nullptr, qkv, 3 * DM, 3 * DM, 0,
                MROWS, 3 * DM, stream);

    attn_kernel<<<dim3(SEQ / 64, NH, BATCH), 256, 0, stream>>>(
        qkv, qkv + DM, qkv + 2 * DM, atb, 3 * DM);

    transpose_cast_kernel<<<dim3(DM / 32, DM / 32), 256, 0, stream>>>(
        wo + (size_t)l * DM * DM, wT, DM, DM, DM);
    launch_gemm(atb, wT, DM, nullptr, h, h, nullptr, DM, DM, 0, MROWS, DM, stream);

    ln_kernel<<<MROWS, 256, 0, stream>>>(h, ln2_g + l * DM, ln2_b + l * DM, hn);

    transpose_cast_kernel<<<dim3(FF / 32, DM / 32), 256, 0, stream>>>(
        w1 + (size_t)l * DM * FF, wT, DM, FF, FF);
    launch_gemm(hn, wT, DM, b1 + (size_t)l * FF, nullptr, nullptr, ffn1, FF, FF, 1,
                MROWS, FF, stream);

    transpose_cast_kernel<<<dim3(DM / 32, FF / 32), 256, 0, stream>>>(
        w2 + (size_t)l * FF * DM, wT, FF, DM, DM);
    launch_gemm(ffn1, wT, FF, b2 + (size_t)l * DM, h, h, nullptr, DM, DM, 0,
                MROWS, DM, stream);
  }

  ln_kernel<<<MROWS, 256, 0, stream>>>(h, lnf_g, lnf_b, hn);
  transpose_cast_kernel<<<dim3(VPAD / 32, DM / 32), 256, 0, stream>>>(
      head_w, headT, DM, VOCAB, VPAD);
  launch_gemm(hn, headT, DM, head_b, nullptr, out, nullptr, VOCAB, VOCAB, 0,
              MROWS, VPAD, stream);
}